// Round 11
// baseline (46.390 us; speedup 1.0000x reference)
//
#include <hip/hip_runtime.h>
#include <hip/hip_bf16.h>
#include <math.h>

// LeanContext1D: x[B,T,C] -> QKV attn (gated by scalar gamma) -> resid -> Linear(C->P) -> LN -> Bezier
// B=2 T=2048 C=1024 H=16 D=64 P=1280. gamma==0 in benchmark inputs => attention path
// early-exits on device-side gamma check (correct for any gamma).
// Hot path: prep (WpT transpose + pa=bf16(x)) -> gemm_proj (128x160, 256 blocks = 1/CU,
// counted-vmcnt pipeline: loads stay in flight across barriers, never vmcnt(0) in loop) -> ln_bezier.

#define H_ 16
#define D_ 64
#define B_ 2
#define T_ 2048
#define C_ 1024
#define P_ 1280
#define M_ 4096

// prep grid layout: [0,1280) WpT tiles | [1280,2304) x-cast (1024 blocks) | [2304,5376) QKV transposes
#define PREP_CAST0 1280
#define PREP_QKV0  2304
#define PREP_GRID  5376

// gemm_proj geometry
#define BM 128
#define BN 160
#define BKp 64

typedef __bf16 bf16_t;
typedef __bf16 v8bf __attribute__((ext_vector_type(8)));
typedef __bf16 v4bf __attribute__((ext_vector_type(4)));
typedef float  v4f  __attribute__((ext_vector_type(4)));

__device__ __forceinline__ void gload_lds16(const void* g, void* l) {
  __builtin_amdgcn_global_load_lds((const __attribute__((address_space(1))) void*)g,
                                   (__attribute__((address_space(3))) void*)l, 16, 0, 0);
}

// stage a [128 rows][32 cols] bf16 tile (qkv path)
template<int LD>
__device__ __forceinline__ void stage_tile128x32(const bf16_t* __restrict__ g, bf16_t* lds, int tid) {
#pragma unroll
  for (int i = 0; i < 2; ++i) {
    int off  = i * 4096 + tid * 16;
    int row  = off >> 6;
    int colb = off & 63;
    const char* gp = (const char*)(g + row * LD) + colb;
    char* lp = (char*)lds + i * 4096 + (tid >> 6) * 1024;
    gload_lds16(gp, lp);
  }
}

__device__ __forceinline__ void stage_f32_tile(const float* __restrict__ src, bf16_t* lds, int tid) {
  int row = tid >> 1, half = tid & 1;
  const float* xp = src + (size_t)row * C_ + half * 16;
  float4 f0 = *(const float4*)(xp);
  float4 f1 = *(const float4*)(xp + 4);
  float4 f2 = *(const float4*)(xp + 8);
  float4 f3 = *(const float4*)(xp + 12);
  v8bf lo = {(__bf16)f0.x, (__bf16)f0.y, (__bf16)f0.z, (__bf16)f0.w,
             (__bf16)f1.x, (__bf16)f1.y, (__bf16)f1.z, (__bf16)f1.w};
  v8bf hi = {(__bf16)f2.x, (__bf16)f2.y, (__bf16)f2.z, (__bf16)f2.w,
             (__bf16)f3.x, (__bf16)f3.y, (__bf16)f3.z, (__bf16)f3.w};
  *(v8bf*)(lds + row * 32 + half * 16)     = lo;
  *(v8bf*)(lds + row * 32 + half * 16 + 8) = hi;
}

// ---- fused prep: Wp transpose (always) + x->bf16 cast (always) + Wq/Wk/Wv transpose (guarded) ----
__global__ __launch_bounds__(256) void prep_kernel(const float* __restrict__ Wp, bf16_t* __restrict__ WpT,
                                                   const float* __restrict__ x, bf16_t* __restrict__ pa,
                                                   const float* __restrict__ Wq, const float* __restrict__ Wk,
                                                   const float* __restrict__ Wv, bf16_t* __restrict__ WT,
                                                   const float* __restrict__ gamma) {
  __shared__ float tile[32][33];
  const int bid = blockIdx.x;
  const float* src;
  bf16_t* dst;
  int N, tile_id;
  if (bid < PREP_CAST0) {                   // Wp: [C][P] -> [P][C]
    src = Wp; dst = WpT; N = P_; tile_id = bid;
  } else if (bid < PREP_QKV0) {             // pa = bf16(x): 1024 blocks x 256 thr x 16 elems
    int base = ((bid - PREP_CAST0) * 256 + threadIdx.x) * 16;
    float4 f0 = *(const float4*)(x + base);
    float4 f1 = *(const float4*)(x + base + 4);
    float4 f2 = *(const float4*)(x + base + 8);
    float4 f3 = *(const float4*)(x + base + 12);
    v8bf lo = {(__bf16)f0.x, (__bf16)f0.y, (__bf16)f0.z, (__bf16)f0.w,
               (__bf16)f1.x, (__bf16)f1.y, (__bf16)f1.z, (__bf16)f1.w};
    v8bf hi = {(__bf16)f2.x, (__bf16)f2.y, (__bf16)f2.z, (__bf16)f2.w,
               (__bf16)f3.x, (__bf16)f3.y, (__bf16)f3.z, (__bf16)f3.w};
    *(v8bf*)(pa + base)     = lo;
    *(v8bf*)(pa + base + 8) = hi;
    return;
  } else {                                  // guarded QKV weight transposes
    if (gamma[0] == 0.0f) return;
    int b2 = bid - PREP_QKV0;
    int w = b2 >> 10;
    tile_id = b2 & 1023;
    src = (w == 0) ? Wq : (w == 1) ? Wk : Wv;
    dst = WT + (size_t)w * C_ * C_;
    N = C_;
  }
  const int nt = N / 32;
  const int n0 = (tile_id % nt) * 32, k0 = (tile_id / nt) * 32;
  const int tx = threadIdx.x & 31, ty = threadIdx.x >> 5;
#pragma unroll
  for (int i = 0; i < 32; i += 8)
    tile[ty + i][tx] = src[(size_t)(k0 + ty + i) * N + n0 + tx];
  __syncthreads();
#pragma unroll
  for (int i = 0; i < 32; i += 8)
    dst[(size_t)(n0 + ty + i) * C_ + k0 + tx] = (bf16_t)tile[tx][ty + i];
}

// ---------------- QKV GEMM (guarded) ----------------
__global__ __launch_bounds__(256) void gemm_qkv(const float* __restrict__ x,
                                                const bf16_t* __restrict__ WT,
                                                const float* __restrict__ bq,
                                                const float* __restrict__ bk,
                                                const float* __restrict__ bv,
                                                bf16_t* __restrict__ q, bf16_t* __restrict__ k,
                                                bf16_t* __restrict__ v,
                                                const float* __restrict__ gamma) {
  if (gamma[0] == 0.0f) return;
  __shared__ alignas(16) bf16_t sA[128 * 32];
  __shared__ alignas(16) bf16_t sB[128 * 32];
  const int tid = threadIdx.x;
  const int m0  = blockIdx.y * 128;
  const int ng0 = blockIdx.x * 128;
  const int w   = ng0 >> 10;
  const int n0  = ng0 & 1023;
  const float*  Ax = x + (size_t)m0 * C_;
  const bf16_t* Bt = WT + (size_t)ng0 * C_;
  const int lane = tid & 63;
  const int wv   = tid >> 6;
  const int wr   = (wv >> 1) * 64;
  const int wc   = (wv & 1) * 64;
  const int kb   = (lane >> 4) * 8;
  const int fr   = lane & 15;
  v4f acc[4][4] = {};
  for (int k0 = 0; k0 < C_; k0 += 32) {
    stage_f32_tile(Ax + k0, sA, tid);
    stage_tile128x32<C_>(Bt + k0, sB, tid);
    __syncthreads();
    v8bf af[4], bfv[4];
#pragma unroll
    for (int f = 0; f < 4; ++f) {
      af[f]  = *(const v8bf*)(sA + (wr + f * 16 + fr) * 32 + kb);
      bfv[f] = *(const v8bf*)(sB + (wc + f * 16 + fr) * 32 + kb);
    }
#pragma unroll
    for (int i = 0; i < 4; ++i)
#pragma unroll
      for (int j = 0; j < 4; ++j)
        acc[i][j] = __builtin_amdgcn_mfma_f32_16x16x32_bf16(af[i], bfv[j], acc[i][j], 0, 0, 0);
    __syncthreads();
  }
  const float* bias = (w == 0) ? bq : (w == 1) ? bk : bv;
  bf16_t* outb = (w == 0) ? q : (w == 1) ? k : v;
#pragma unroll
  for (int fj = 0; fj < 4; ++fj) {
    int colL = n0 + wc + fj * 16 + fr;
    float bsv = bias[colL];
    int hh = colL >> 6, dd = colL & 63;
#pragma unroll
    for (int fi = 0; fi < 4; ++fi) {
#pragma unroll
      for (int i = 0; i < 4; ++i) {
        int m = m0 + wr + fi * 16 + (lane >> 4) * 4 + i;
        int bb = m >> 11, tt = m & 2047;
        outb[(((size_t)bb * H_ + hh) * T_ + tt) * D_ + dd] = (bf16_t)(acc[fi][fj][i] + bsv);
      }
    }
  }
}

// ---- flash attention + fused residual (guarded): overwrites pa = bf16(gamma*attn + x) ----
__global__ __launch_bounds__(256) void attn_kernel(const bf16_t* __restrict__ q,
                                                   const bf16_t* __restrict__ k,
                                                   const bf16_t* __restrict__ v,
                                                   const float* __restrict__ x,
                                                   bf16_t* __restrict__ pa,
                                                   const float* __restrict__ gamma) {
  const float g = gamma[0];
  if (g == 0.0f) return;
  __shared__ alignas(16) bf16_t sP[4][16 * 32];
  const int tid = threadIdx.x, lane = tid & 63, wv = tid >> 6;
  const int bh = blockIdx.y;
  const int q0 = blockIdx.x * 64 + wv * 16;
  const bf16_t* Q = q + (size_t)bh * T_ * D_;
  const bf16_t* K = k + (size_t)bh * T_ * D_;
  const bf16_t* V = v + (size_t)bh * T_ * D_;
  const int fr = lane & 15, kb = (lane >> 4) * 8;
  v8bf qf[2];
  qf[0] = *(const v8bf*)(Q + (q0 + fr) * 64 + kb);
  qf[1] = *(const v8bf*)(Q + (q0 + fr) * 64 + 32 + kb);
  float mrow[4], lrow[4];
  v4f oacc[4] = {};
#pragma unroll
  for (int i = 0; i < 4; ++i) { mrow[i] = -1e30f; lrow[i] = 0.f; }
  for (int kv0 = 0; kv0 < T_; kv0 += 32) {
    v4f s[2] = {};
#pragma unroll
    for (int nf = 0; nf < 2; ++nf) {
      v8bf k0f = *(const v8bf*)(K + (kv0 + nf * 16 + fr) * 64 + kb);
      v8bf k1f = *(const v8bf*)(K + (kv0 + nf * 16 + fr) * 64 + 32 + kb);
      s[nf] = __builtin_amdgcn_mfma_f32_16x16x32_bf16(qf[0], k0f, s[nf], 0, 0, 0);
      s[nf] = __builtin_amdgcn_mfma_f32_16x16x32_bf16(qf[1], k1f, s[nf], 0, 0, 0);
    }
#pragma unroll
    for (int nf = 0; nf < 2; ++nf)
#pragma unroll
      for (int i = 0; i < 4; ++i) s[nf][i] *= 0.125f;
    float fac[4];
#pragma unroll
    for (int i = 0; i < 4; ++i) {
      float mx = fmaxf(s[0][i], s[1][i]);
      for (int off = 1; off < 16; off <<= 1) mx = fmaxf(mx, __shfl_xor(mx, off));
      float mn = fmaxf(mrow[i], mx);
      fac[i] = expf(mrow[i] - mn);
      mrow[i] = mn;
      float p0 = expf(s[0][i] - mn);
      float p1 = expf(s[1][i] - mn);
      s[0][i] = p0; s[1][i] = p1;
      float ts = p0 + p1;
      for (int off = 1; off < 16; off <<= 1) ts += __shfl_xor(ts, off);
      lrow[i] = lrow[i] * fac[i] + ts;
#pragma unroll
      for (int df = 0; df < 4; ++df) oacc[df][i] *= fac[i];
    }
    bf16_t* myP = &sP[wv][0];
#pragma unroll
    for (int nf = 0; nf < 2; ++nf)
#pragma unroll
      for (int i = 0; i < 4; ++i)
        myP[((lane >> 4) * 4 + i) * 32 + nf * 16 + fr] = (bf16_t)s[nf][i];
    __syncthreads();
    v8bf pf = *(const v8bf*)(myP + fr * 32 + kb);
#pragma unroll
    for (int df = 0; df < 4; ++df) {
      v8bf vf;
#pragma unroll
      for (int j = 0; j < 8; ++j) vf[j] = V[(size_t)(kv0 + kb + j) * 64 + df * 16 + fr];
      oacc[df] = __builtin_amdgcn_mfma_f32_16x16x32_bf16(pf, vf, oacc[df], 0, 0, 0);
    }
    __syncthreads();
  }
  const int b = bh >> 4, hh = bh & 15;
#pragma unroll
  for (int df = 0; df < 4; ++df)
#pragma unroll
    for (int i = 0; i < 4; ++i) {
      int qr = q0 + (lane >> 4) * 4 + i;
      size_t m = (size_t)b * T_ + qr;
      int c = hh * 64 + df * 16 + fr;
      float o = oacc[df][i] / lrow[i];
      float xv = x[m * C_ + c];
      pa[m * C_ + c] = (bf16_t)fmaf(g, o, xv);
    }
}

// ---- projection GEMM: pa[4096,1024]bf16 x WpT[1280][1024] -> h bf16
// 128x160 tiles, 256 blocks (1/CU), 4 waves, wave tile 64x80 (acc 4x5)
// counted-vmcnt pipeline (T3/T4): 2 tiles in flight, vmcnt(9) in steady state (never 0),
// raw s_barrier (no implicit drain); STAGE for t+2 issued after all waves consumed the buffer.
__global__ __launch_bounds__(256) void gemm_proj(const bf16_t* __restrict__ pa,
                                                 const bf16_t* __restrict__ WpT,
                                                 const float* __restrict__ bp,
                                                 bf16_t* __restrict__ h) {
  __shared__ alignas(16) bf16_t sA[2][BM * BKp];   // 2 x 16 KB
  __shared__ alignas(16) bf16_t sB[2][BN * BKp];   // 2 x 20 KB
  const int tid = threadIdx.x, lane = tid & 63, wv = tid >> 6;
  // XCD-chunked bijective swizzle: 256 blocks; XCD x gets wg [x*32, x*32+32) = 4 m-panels x all 8 n
  const int bid = blockIdx.x;
  const int wg  = (bid & 7) * 32 + (bid >> 3);
  const int m0  = (wg >> 3) * BM;
  const int n0  = (wg & 7) * BN;
  // wave tile: 64 x 80 (2x2 wave grid)
  const int wr = (wv >> 1) * 64;
  const int wc = (wv & 1) * 80;
  const int fr = lane & 15, q = lane >> 4;
  // staging: inverse-swizzled source (rule 21). chunk c covers LDS bytes [c*1024,(c+1)*1024).
  const int srow = lane >> 3;                      // row within chunk (0..7)
  const int scolb = (((lane & 7) ^ srow) << 4);    // source byte col (0..127)
  const bf16_t* Abase = pa  + (size_t)m0 * C_;
  const bf16_t* Bbase = WpT + (size_t)n0 * C_;

  v4f acc[4][5] = {};

// exactly 9 global_load_lds instructions per wave per call -> vmcnt granularity = 9
#define STAGE_PROJ(buf, kk)                                                          \
  do {                                                                               \
    _Pragma("unroll")                                                                \
    for (int ci = 0; ci < 9; ++ci) {                                                 \
      int c = wv + ci * 4;                                                           \
      if (c < 16) {                                                                  \
        int row = c * 8 + srow;                                                      \
        const char* gp = (const char*)(Abase + (size_t)row * C_ + (kk)) + scolb;     \
        gload_lds16(gp, (char*)&sA[buf][0] + c * 1024);                              \
      } else {                                                                       \
        int row = (c - 16) * 8 + srow;                                               \
        const char* gp = (const char*)(Bbase + (size_t)row * C_ + (kk)) + scolb;     \
        gload_lds16(gp, (char*)&sB[buf][0] + (c - 16) * 1024);                       \
      }                                                                              \
    }                                                                                \
  } while (0)

#define COMPUTE_PROJ(buf)                                                            \
  do {                                                                               \
    _Pragma("unroll")                                                                \
    for (int kc = 0; kc < 2; ++kc) {                                                 \
      const int c16 = kc * 4 + q;                                                    \
      const int sw  = (c16 ^ (fr & 7)) * 8;                                          \
      v8bf av[4], bv5[5];                                                            \
      _Pragma("unroll")                                                              \
      for (int fi = 0; fi < 4; ++fi)                                                 \
        av[fi] = *(const v8bf*)(&sA[buf][0] + (wr + fi * 16 + fr) * BKp + sw);       \
      _Pragma("unroll")                                                              \
      for (int fj = 0; fj < 5; ++fj)                                                 \
        bv5[fj] = *(const v8bf*)(&sB[buf][0] + (wc + fj * 16 + fr) * BKp + sw);      \
      _Pragma("unroll")                                                              \
      for (int fi = 0; fi < 4; ++fi)                                                 \
        _Pragma("unroll")                                                            \
        for (int fj = 0; fj < 5; ++fj)                                               \
          acc[fi][fj] = __builtin_amdgcn_mfma_f32_16x16x32_bf16(av[fi], bv5[fj],     \
                                                                acc[fi][fj], 0, 0, 0);\
    }                                                                                \
  } while (0)

  // prologue: two tiles in flight (18 loads/wave)
  STAGE_PROJ(0, 0);
  STAGE_PROJ(1, BKp);
  int cur = 0;
#pragma unroll 1
  for (int t = 0; t < 16; ++t) {
    // steady state: 18 outstanding; wait until only the newer 9 remain -> tile t landed.
    if (t < 15) asm volatile("s_waitcnt vmcnt(9)" ::: "memory");
    else        asm volatile("s_waitcnt vmcnt(0)" ::: "memory");
    __builtin_amdgcn_s_barrier();            // all waves: buf[cur] ready
    COMPUTE_PROJ(cur);
    __builtin_amdgcn_sched_barrier(0);       // pin MFMAs before the barrier (rule 18)
    __builtin_amdgcn_s_barrier();            // all waves done reading buf[cur]
    if (t + 2 < 16) STAGE_PROJ(cur, (t + 2) * BKp);  // overwrite consumed buffer
    cur ^= 1;
  }

#undef STAGE_PROJ
#undef COMPUTE_PROJ

  // epilogue: + bias, cast bf16
#pragma unroll
  for (int fj = 0; fj < 5; ++fj) {
    int n = n0 + wc + fj * 16 + fr;
    float bsv = bp[n];
#pragma unroll
    for (int fi = 0; fi < 4; ++fi) {
#pragma unroll
      for (int i = 0; i < 4; ++i) {
        int m = m0 + wr + fi * 16 + q * 4 + i;
        h[(size_t)m * P_ + n] = (bf16_t)(acc[fi][fj][i] + bsv);
      }
    }
  }
}

// ---------------- LayerNorm over P + Bezier: one WAVE per row ----------------
__global__ __launch_bounds__(256) void ln_bezier(const bf16_t* __restrict__ h,
                                                 const float* __restrict__ ln_g,
                                                 const float* __restrict__ ln_b,
                                                 const float* __restrict__ bez,
                                                 float* __restrict__ out) {
  const int lane = threadIdx.x & 63;
  const int row  = blockIdx.x * 4 + (threadIdx.x >> 6);
  const bf16_t* hr = h + (size_t)row * P_;
  float v[20];
  float s = 0.f, ss = 0.f;
#pragma unroll
  for (int p = 0; p < 5; ++p) {
    v4bf hv = *(const v4bf*)(hr + p * 256 + lane * 4);
#pragma unroll
    for (int j = 0; j < 4; ++j) {
      float f = (float)hv[j];
      v[p * 4 + j] = f;
      s += f; ss += f * f;
    }
  }
#pragma unroll
  for (int off = 1; off < 64; off <<= 1) {
    s  += __shfl_xor(s, off);
    ss += __shfl_xor(ss, off);
  }
  const float inv = 1.0f / (float)P_;
  float mu = s * inv;
  float var = ss * inv - mu * mu;
  float rstd = rsqrtf(var + 1e-5f);
  float p0 = bez[0], p1 = bez[1], p2 = bez[2], p3 = bez[3];
#pragma unroll
  for (int p = 0; p < 5; ++p) {
    int c = p * 256 + lane * 4;
    float4 g4 = *(const float4*)(ln_g + c);
    float4 b4 = *(const float4*)(ln_b + c);
    float4 o4;
    float gg[4] = {g4.x, g4.y, g4.z, g4.w};
    float bb[4] = {b4.x, b4.y, b4.z, b4.w};
    float oo[4];
#pragma unroll
    for (int j = 0; j < 4; ++j) {
      float y = (v[p * 4 + j] - mu) * rstd * gg[j] + bb[j];
      float sg = 1.0f / (1.0f + expf(-y));
      float u = 1.0f - sg;
      oo[j] = u * u * u * p0 + 3.0f * u * u * sg * p1 + 3.0f * u * sg * sg * p2 + sg * sg * sg * p3;
    }
    o4.x = oo[0]; o4.y = oo[1]; o4.z = oo[2]; o4.w = oo[3];
    *(float4*)(out + (size_t)row * P_ + c) = o4;
  }
}

extern "C" void kernel_launch(void* const* d_in, const int* in_sizes, int n_in,
                              void* d_out, int out_size, void* d_ws, size_t ws_size,
                              hipStream_t stream) {
  const float* x     = (const float*)d_in[0];
  const float* Wq    = (const float*)d_in[1];
  const float* bq    = (const float*)d_in[2];
  const float* Wk    = (const float*)d_in[3];
  const float* bk    = (const float*)d_in[4];
  const float* Wv    = (const float*)d_in[5];
  const float* bv    = (const float*)d_in[6];
  const float* gamma = (const float*)d_in[7];
  const float* Wp    = (const float*)d_in[8];
  const float* bp    = (const float*)d_in[9];
  const float* ln_g  = (const float*)d_in[10];
  const float* ln_b  = (const float*)d_in[11];
  const float* bez   = (const float*)d_in[12];
  float* out = (float*)d_out;

  char* ws = (char*)d_ws;
  bf16_t* qb  = (bf16_t*)(ws);                          //  8 MB [B,H,T,D]
  bf16_t* kb_ = (bf16_t*)(ws + (size_t)8  * 1048576);   //  8 MB
  bf16_t* vb  = (bf16_t*)(ws + (size_t)16 * 1048576);   //  8 MB
  bf16_t* WT  = (bf16_t*)(ws + (size_t)24 * 1048576);   //  6 MB (WqT|WkT|WvT)
  bf16_t* pa  = (bf16_t*)(ws + (size_t)30 * 1048576);   //  8 MB proj A input (bf16)
  bf16_t* WpT = (bf16_t*)(ws + (size_t)38 * 1048576);   //  2.5 MB
  bf16_t* hb  = (bf16_t*)(ws + (size_t)41 * 1048576);   // 10 MB

  prep_kernel<<<PREP_GRID, 256, 0, stream>>>(Wp, WpT, x, pa, Wq, Wk, Wv, WT, gamma);
  gemm_qkv<<<dim3(24, 32), 256, 0, stream>>>(x, WT, bq, bk, bv, qb, kb_, vb, gamma);
  attn_kernel<<<dim3(32, 32), 256, 0, stream>>>(qb, kb_, vb, x, pa, gamma);
  gemm_proj<<<256, 256, 0, stream>>>(pa, WpT, bp, hb);
  ln_bezier<<<1024, 256, 0, stream>>>(hb, ln_g, ln_b, bez, out);
}

// Round 12
// 42.554 us; speedup vs baseline: 1.0902x; 1.0902x over previous
//
#include <hip/hip_runtime.h>
#include <hip/hip_bf16.h>
#include <math.h>

// LeanContext1D: x[B,T,C] -> QKV attn (gated by scalar gamma) -> resid -> Linear(C->P) -> LN -> Bezier
// B=2 T=2048 C=1024 H=16 D=64 P=1280. gamma==0 in benchmark inputs => attention path
// early-exits on device-side gamma check (correct for any gamma).
// Hot path: prep (WpT transpose + pa=bf16(x)) -> gemm_proj (64x160 tiles, 512 blocks = 2/CU for
// cross-block latency hiding (m114), counted-vmcnt pipeline) -> ln_bezier.

#define H_ 16
#define D_ 64
#define B_ 2
#define T_ 2048
#define C_ 1024
#define P_ 1280
#define M_ 4096

// prep grid layout: [0,1280) WpT tiles | [1280,2304) x-cast (1024 blocks) | [2304,5376) QKV transposes
#define PREP_CAST0 1280
#define PREP_QKV0  2304
#define PREP_GRID  5376

// gemm_proj geometry: 64x160 tile, BK=64, grid 512 (64 m-panels x 8 n-tiles) = 2 blocks/CU
#define BM 64
#define BN 160
#define BKp 64

typedef __bf16 bf16_t;
typedef __bf16 v8bf __attribute__((ext_vector_type(8)));
typedef __bf16 v4bf __attribute__((ext_vector_type(4)));
typedef float  v4f  __attribute__((ext_vector_type(4)));

__device__ __forceinline__ void gload_lds16(const void* g, void* l) {
  __builtin_amdgcn_global_load_lds((const __attribute__((address_space(1))) void*)g,
                                   (__attribute__((address_space(3))) void*)l, 16, 0, 0);
}

// stage a [128 rows][32 cols] bf16 tile (qkv path)
template<int LD>
__device__ __forceinline__ void stage_tile128x32(const bf16_t* __restrict__ g, bf16_t* lds, int tid) {
#pragma unroll
  for (int i = 0; i < 2; ++i) {
    int off  = i * 4096 + tid * 16;
    int row  = off >> 6;
    int colb = off & 63;
    const char* gp = (const char*)(g + row * LD) + colb;
    char* lp = (char*)lds + i * 4096 + (tid >> 6) * 1024;
    gload_lds16(gp, lp);
  }
}

__device__ __forceinline__ void stage_f32_tile(const float* __restrict__ src, bf16_t* lds, int tid) {
  int row = tid >> 1, half = tid & 1;
  const float* xp = src + (size_t)row * C_ + half * 16;
  float4 f0 = *(const float4*)(xp);
  float4 f1 = *(const float4*)(xp + 4);
  float4 f2 = *(const float4*)(xp + 8);
  float4 f3 = *(const float4*)(xp + 12);
  v8bf lo = {(__bf16)f0.x, (__bf16)f0.y, (__bf16)f0.z, (__bf16)f0.w,
             (__bf16)f1.x, (__bf16)f1.y, (__bf16)f1.z, (__bf16)f1.w};
  v8bf hi = {(__bf16)f2.x, (__bf16)f2.y, (__bf16)f2.z, (__bf16)f2.w,
             (__bf16)f3.x, (__bf16)f3.y, (__bf16)f3.z, (__bf16)f3.w};
  *(v8bf*)(lds + row * 32 + half * 16)     = lo;
  *(v8bf*)(lds + row * 32 + half * 16 + 8) = hi;
}

// ---- fused prep: Wp transpose (always) + x->bf16 cast (always) + Wq/Wk/Wv transpose (guarded) ----
__global__ __launch_bounds__(256) void prep_kernel(const float* __restrict__ Wp, bf16_t* __restrict__ WpT,
                                                   const float* __restrict__ x, bf16_t* __restrict__ pa,
                                                   const float* __restrict__ Wq, const float* __restrict__ Wk,
                                                   const float* __restrict__ Wv, bf16_t* __restrict__ WT,
                                                   const float* __restrict__ gamma) {
  __shared__ float tile[32][33];
  const int bid = blockIdx.x;
  const float* src;
  bf16_t* dst;
  int N, tile_id;
  if (bid < PREP_CAST0) {                   // Wp: [C][P] -> [P][C]
    src = Wp; dst = WpT; N = P_; tile_id = bid;
  } else if (bid < PREP_QKV0) {             // pa = bf16(x): 1024 blocks x 256 thr x 16 elems
    int base = ((bid - PREP_CAST0) * 256 + threadIdx.x) * 16;
    float4 f0 = *(const float4*)(x + base);
    float4 f1 = *(const float4*)(x + base + 4);
    float4 f2 = *(const float4*)(x + base + 8);
    float4 f3 = *(const float4*)(x + base + 12);
    v8bf lo = {(__bf16)f0.x, (__bf16)f0.y, (__bf16)f0.z, (__bf16)f0.w,
               (__bf16)f1.x, (__bf16)f1.y, (__bf16)f1.z, (__bf16)f1.w};
    v8bf hi = {(__bf16)f2.x, (__bf16)f2.y, (__bf16)f2.z, (__bf16)f2.w,
               (__bf16)f3.x, (__bf16)f3.y, (__bf16)f3.z, (__bf16)f3.w};
    *(v8bf*)(pa + base)     = lo;
    *(v8bf*)(pa + base + 8) = hi;
    return;
  } else {                                  // guarded QKV weight transposes
    if (gamma[0] == 0.0f) return;
    int b2 = bid - PREP_QKV0;
    int w = b2 >> 10;
    tile_id = b2 & 1023;
    src = (w == 0) ? Wq : (w == 1) ? Wk : Wv;
    dst = WT + (size_t)w * C_ * C_;
    N = C_;
  }
  const int nt = N / 32;
  const int n0 = (tile_id % nt) * 32, k0 = (tile_id / nt) * 32;
  const int tx = threadIdx.x & 31, ty = threadIdx.x >> 5;
#pragma unroll
  for (int i = 0; i < 32; i += 8)
    tile[ty + i][tx] = src[(size_t)(k0 + ty + i) * N + n0 + tx];
  __syncthreads();
#pragma unroll
  for (int i = 0; i < 32; i += 8)
    dst[(size_t)(n0 + ty + i) * C_ + k0 + tx] = (bf16_t)tile[tx][ty + i];
}

// ---------------- QKV GEMM (guarded) ----------------
__global__ __launch_bounds__(256) void gemm_qkv(const float* __restrict__ x,
                                                const bf16_t* __restrict__ WT,
                                                const float* __restrict__ bq,
                                                const float* __restrict__ bk,
                                                const float* __restrict__ bv,
                                                bf16_t* __restrict__ q, bf16_t* __restrict__ k,
                                                bf16_t* __restrict__ v,
                                                const float* __restrict__ gamma) {
  if (gamma[0] == 0.0f) return;
  __shared__ alignas(16) bf16_t sA[128 * 32];
  __shared__ alignas(16) bf16_t sB[128 * 32];
  const int tid = threadIdx.x;
  const int m0  = blockIdx.y * 128;
  const int ng0 = blockIdx.x * 128;
  const int w   = ng0 >> 10;
  const int n0  = ng0 & 1023;
  const float*  Ax = x + (size_t)m0 * C_;
  const bf16_t* Bt = WT + (size_t)ng0 * C_;
  const int lane = tid & 63;
  const int wv   = tid >> 6;
  const int wr   = (wv >> 1) * 64;
  const int wc   = (wv & 1) * 64;
  const int kb   = (lane >> 4) * 8;
  const int fr   = lane & 15;
  v4f acc[4][4] = {};
  for (int k0 = 0; k0 < C_; k0 += 32) {
    stage_f32_tile(Ax + k0, sA, tid);
    stage_tile128x32<C_>(Bt + k0, sB, tid);
    __syncthreads();
    v8bf af[4], bfv[4];
#pragma unroll
    for (int f = 0; f < 4; ++f) {
      af[f]  = *(const v8bf*)(sA + (wr + f * 16 + fr) * 32 + kb);
      bfv[f] = *(const v8bf*)(sB + (wc + f * 16 + fr) * 32 + kb);
    }
#pragma unroll
    for (int i = 0; i < 4; ++i)
#pragma unroll
      for (int j = 0; j < 4; ++j)
        acc[i][j] = __builtin_amdgcn_mfma_f32_16x16x32_bf16(af[i], bfv[j], acc[i][j], 0, 0, 0);
    __syncthreads();
  }
  const float* bias = (w == 0) ? bq : (w == 1) ? bk : bv;
  bf16_t* outb = (w == 0) ? q : (w == 1) ? k : v;
#pragma unroll
  for (int fj = 0; fj < 4; ++fj) {
    int colL = n0 + wc + fj * 16 + fr;
    float bsv = bias[colL];
    int hh = colL >> 6, dd = colL & 63;
#pragma unroll
    for (int fi = 0; fi < 4; ++fi) {
#pragma unroll
      for (int i = 0; i < 4; ++i) {
        int m = m0 + wr + fi * 16 + (lane >> 4) * 4 + i;
        int bb = m >> 11, tt = m & 2047;
        outb[(((size_t)bb * H_ + hh) * T_ + tt) * D_ + dd] = (bf16_t)(acc[fi][fj][i] + bsv);
      }
    }
  }
}

// ---- flash attention + fused residual (guarded): overwrites pa = bf16(gamma*attn + x) ----
__global__ __launch_bounds__(256) void attn_kernel(const bf16_t* __restrict__ q,
                                                   const bf16_t* __restrict__ k,
                                                   const bf16_t* __restrict__ v,
                                                   const float* __restrict__ x,
                                                   bf16_t* __restrict__ pa,
                                                   const float* __restrict__ gamma) {
  const float g = gamma[0];
  if (g == 0.0f) return;
  __shared__ alignas(16) bf16_t sP[4][16 * 32];
  const int tid = threadIdx.x, lane = tid & 63, wv = tid >> 6;
  const int bh = blockIdx.y;
  const int q0 = blockIdx.x * 64 + wv * 16;
  const bf16_t* Q = q + (size_t)bh * T_ * D_;
  const bf16_t* K = k + (size_t)bh * T_ * D_;
  const bf16_t* V = v + (size_t)bh * T_ * D_;
  const int fr = lane & 15, kb = (lane >> 4) * 8;
  v8bf qf[2];
  qf[0] = *(const v8bf*)(Q + (q0 + fr) * 64 + kb);
  qf[1] = *(const v8bf*)(Q + (q0 + fr) * 64 + 32 + kb);
  float mrow[4], lrow[4];
  v4f oacc[4] = {};
#pragma unroll
  for (int i = 0; i < 4; ++i) { mrow[i] = -1e30f; lrow[i] = 0.f; }
  for (int kv0 = 0; kv0 < T_; kv0 += 32) {
    v4f s[2] = {};
#pragma unroll
    for (int nf = 0; nf < 2; ++nf) {
      v8bf k0f = *(const v8bf*)(K + (kv0 + nf * 16 + fr) * 64 + kb);
      v8bf k1f = *(const v8bf*)(K + (kv0 + nf * 16 + fr) * 64 + 32 + kb);
      s[nf] = __builtin_amdgcn_mfma_f32_16x16x32_bf16(qf[0], k0f, s[nf], 0, 0, 0);
      s[nf] = __builtin_amdgcn_mfma_f32_16x16x32_bf16(qf[1], k1f, s[nf], 0, 0, 0);
    }
#pragma unroll
    for (int nf = 0; nf < 2; ++nf)
#pragma unroll
      for (int i = 0; i < 4; ++i) s[nf][i] *= 0.125f;
    float fac[4];
#pragma unroll
    for (int i = 0; i < 4; ++i) {
      float mx = fmaxf(s[0][i], s[1][i]);
      for (int off = 1; off < 16; off <<= 1) mx = fmaxf(mx, __shfl_xor(mx, off));
      float mn = fmaxf(mrow[i], mx);
      fac[i] = expf(mrow[i] - mn);
      mrow[i] = mn;
      float p0 = expf(s[0][i] - mn);
      float p1 = expf(s[1][i] - mn);
      s[0][i] = p0; s[1][i] = p1;
      float ts = p0 + p1;
      for (int off = 1; off < 16; off <<= 1) ts += __shfl_xor(ts, off);
      lrow[i] = lrow[i] * fac[i] + ts;
#pragma unroll
      for (int df = 0; df < 4; ++df) oacc[df][i] *= fac[i];
    }
    bf16_t* myP = &sP[wv][0];
#pragma unroll
    for (int nf = 0; nf < 2; ++nf)
#pragma unroll
      for (int i = 0; i < 4; ++i)
        myP[((lane >> 4) * 4 + i) * 32 + nf * 16 + fr] = (bf16_t)s[nf][i];
    __syncthreads();
    v8bf pf = *(const v8bf*)(myP + fr * 32 + kb);
#pragma unroll
    for (int df = 0; df < 4; ++df) {
      v8bf vf;
#pragma unroll
      for (int j = 0; j < 8; ++j) vf[j] = V[(size_t)(kv0 + kb + j) * 64 + df * 16 + fr];
      oacc[df] = __builtin_amdgcn_mfma_f32_16x16x32_bf16(pf, vf, oacc[df], 0, 0, 0);
    }
    __syncthreads();
  }
  const int b = bh >> 4, hh = bh & 15;
#pragma unroll
  for (int df = 0; df < 4; ++df)
#pragma unroll
    for (int i = 0; i < 4; ++i) {
      int qr = q0 + (lane >> 4) * 4 + i;
      size_t m = (size_t)b * T_ + qr;
      int c = hh * 64 + df * 16 + fr;
      float o = oacc[df][i] / lrow[i];
      float xv = x[m * C_ + c];
      pa[m * C_ + c] = (bf16_t)fmaf(g, o, xv);
    }
}

// ---- projection GEMM: pa[4096,1024]bf16 x WpT[1280][1024] -> h bf16
// 64x160 tiles, 512 blocks (= 2 blocks/CU: cross-block latency hiding, m114), 4 waves,
// wave tile 32x80 (acc 2x5). Counted-vmcnt pipeline: 7 loads/wave/STAGE (uniform),
// vmcnt(7) steady state, raw s_barrier.
__global__ __launch_bounds__(256) void gemm_proj(const bf16_t* __restrict__ pa,
                                                 const bf16_t* __restrict__ WpT,
                                                 const float* __restrict__ bp,
                                                 bf16_t* __restrict__ h) {
  __shared__ alignas(16) bf16_t sA[2][BM * BKp];   // 2 x 8 KB
  __shared__ alignas(16) bf16_t sB[2][BN * BKp];   // 2 x 20 KB
  const int tid = threadIdx.x, lane = tid & 63, wv = tid >> 6;
  // XCD-chunked bijective swizzle: 512 blocks; XCD x gets wg [x*64,(x+1)*64) = 8 m-panels x 8 n
  // (working set 1 MB A + 2.5 MB B < 4 MB L2)
  const int bid = blockIdx.x;
  const int wg  = (bid & 7) * 64 + (bid >> 3);
  const int m0  = (wg >> 3) * BM;
  const int n0  = (wg & 7) * BN;
  // wave tile: 32 x 80 (2m x 2n wave grid)
  const int wr = (wv >> 1) * 32;
  const int wc = (wv & 1) * 80;
  const int fr = lane & 15, q = lane >> 4;
  // staging: inverse-swizzled source (rule 21). chunk c covers LDS bytes [c*1024,(c+1)*1024).
  const int srow = lane >> 3;                      // row within chunk (0..7)
  const int scolb = (((lane & 7) ^ srow) << 4);    // source byte col (0..127)
  const bf16_t* Abase = pa  + (size_t)m0 * C_;
  const bf16_t* Bbase = WpT + (size_t)n0 * C_;

  v4f acc[2][5] = {};

// 28 chunks total (A: 0-7, B: 8-27); wave wv takes c = wv+4*ci, ci<7 -> exactly 7 loads/wave
#define STAGE_PROJ(buf, kk)                                                          \
  do {                                                                               \
    _Pragma("unroll")                                                                \
    for (int ci = 0; ci < 7; ++ci) {                                                 \
      int c = wv + ci * 4;                                                           \
      if (c < 8) {                                                                   \
        int row = c * 8 + srow;                                                      \
        const char* gp = (const char*)(Abase + (size_t)row * C_ + (kk)) + scolb;     \
        gload_lds16(gp, (char*)&sA[buf][0] + c * 1024);                              \
      } else {                                                                       \
        int row = (c - 8) * 8 + srow;                                                \
        const char* gp = (const char*)(Bbase + (size_t)row * C_ + (kk)) + scolb;     \
        gload_lds16(gp, (char*)&sB[buf][0] + (c - 8) * 1024);                        \
      }                                                                              \
    }                                                                                \
  } while (0)

#define COMPUTE_PROJ(buf)                                                            \
  do {                                                                               \
    _Pragma("unroll")                                                                \
    for (int kc = 0; kc < 2; ++kc) {                                                 \
      const int c16 = kc * 4 + q;                                                    \
      const int sw  = (c16 ^ (fr & 7)) * 8;                                          \
      v8bf av[2], bv5[5];                                                            \
      _Pragma("unroll")                                                              \
      for (int fi = 0; fi < 2; ++fi)                                                 \
        av[fi] = *(const v8bf*)(&sA[buf][0] + (wr + fi * 16 + fr) * BKp + sw);       \
      _Pragma("unroll")                                                              \
      for (int fj = 0; fj < 5; ++fj)                                                 \
        bv5[fj] = *(const v8bf*)(&sB[buf][0] + (wc + fj * 16 + fr) * BKp + sw);      \
      _Pragma("unroll")                                                              \
      for (int fi = 0; fi < 2; ++fi)                                                 \
        _Pragma("unroll")                                                            \
        for (int fj = 0; fj < 5; ++fj)                                               \
          acc[fi][fj] = __builtin_amdgcn_mfma_f32_16x16x32_bf16(av[fi], bv5[fj],     \
                                                                acc[fi][fj], 0, 0, 0);\
    }                                                                                \
  } while (0)

  // prologue: two tiles in flight (14 loads/wave)
  STAGE_PROJ(0, 0);
  STAGE_PROJ(1, BKp);
  int cur = 0;
#pragma unroll 1
  for (int t = 0; t < 16; ++t) {
    // steady state: 14 outstanding; wait until only the newer 7 remain -> tile t landed.
    if (t < 15) asm volatile("s_waitcnt vmcnt(7)" ::: "memory");
    else        asm volatile("s_waitcnt vmcnt(0)" ::: "memory");
    __builtin_amdgcn_s_barrier();            // all waves: buf[cur] ready
    COMPUTE_PROJ(cur);
    __builtin_amdgcn_sched_barrier(0);       // pin MFMAs before the barrier (rule 18)
    __builtin_amdgcn_s_barrier();            // all waves done reading buf[cur]
    if (t + 2 < 16) STAGE_PROJ(cur, (t + 2) * BKp);  // overwrite consumed buffer
    cur ^= 1;
  }

#undef STAGE_PROJ
#undef COMPUTE_PROJ

  // epilogue: + bias, cast bf16
#pragma unroll
  for (int fj = 0; fj < 5; ++fj) {
    int n = n0 + wc + fj * 16 + fr;
    float bsv = bp[n];
#pragma unroll
    for (int fi = 0; fi < 2; ++fi) {
#pragma unroll
      for (int i = 0; i < 4; ++i) {
        int m = m0 + wr + fi * 16 + q * 4 + i;
        h[(size_t)m * P_ + n] = (bf16_t)(acc[fi][fj][i] + bsv);
      }
    }
  }
}

// ---------------- LayerNorm over P + Bezier: one WAVE per row ----------------
__global__ __launch_bounds__(256) void ln_bezier(const bf16_t* __restrict__ h,
                                                 const float* __restrict__ ln_g,
                                                 const float* __restrict__ ln_b,
                                                 const float* __restrict__ bez,
                                                 float* __restrict__ out) {
  const int lane = threadIdx.x & 63;
  const int row  = blockIdx.x * 4 + (threadIdx.x >> 6);
  const bf16_t* hr = h + (size_t)row * P_;
  float v[20];
  float s = 0.f, ss = 0.f;
#pragma unroll
  for (int p = 0; p < 5; ++p) {
    v4bf hv = *(const v4bf*)(hr + p * 256 + lane * 4);
#pragma unroll
    for (int j = 0; j < 4; ++j) {
      float f = (float)hv[j];
      v[p * 4 + j] = f;
      s += f; ss += f * f;
    }
  }
#pragma unroll
  for (int off = 1; off < 64; off <<= 1) {
    s  += __shfl_xor(s, off);
    ss += __shfl_xor(ss, off);
  }
  const float inv = 1.0f / (float)P_;
  float mu = s * inv;
  float var = ss * inv - mu * mu;
  float rstd = rsqrtf(var + 1e-5f);
  float p0 = bez[0], p1 = bez[1], p2 = bez[2], p3 = bez[3];
#pragma unroll
  for (int p = 0; p < 5; ++p) {
    int c = p * 256 + lane * 4;
    float4 g4 = *(const float4*)(ln_g + c);
    float4 b4 = *(const float4*)(ln_b + c);
    float4 o4;
    float gg[4] = {g4.x, g4.y, g4.z, g4.w};
    float bb[4] = {b4.x, b4.y, b4.z, b4.w};
    float oo[4];
#pragma unroll
    for (int j = 0; j < 4; ++j) {
      float y = (v[p * 4 + j] - mu) * rstd * gg[j] + bb[j];
      float sg = 1.0f / (1.0f + expf(-y));
      float u = 1.0f - sg;
      oo[j] = u * u * u * p0 + 3.0f * u * u * sg * p1 + 3.0f * u * sg * sg * p2 + sg * sg * sg * p3;
    }
    o4.x = oo[0]; o4.y = oo[1]; o4.z = oo[2]; o4.w = oo[3];
    *(float4*)(out + (size_t)row * P_ + c) = o4;
  }
}

extern "C" void kernel_launch(void* const* d_in, const int* in_sizes, int n_in,
                              void* d_out, int out_size, void* d_ws, size_t ws_size,
                              hipStream_t stream) {
  const float* x     = (const float*)d_in[0];
  const float* Wq    = (const float*)d_in[1];
  const float* bq    = (const float*)d_in[2];
  const float* Wk    = (const float*)d_in[3];
  const float* bk    = (const float*)d_in[4];
  const float* Wv    = (const float*)d_in[5];
  const float* bv    = (const float*)d_in[6];
  const float* gamma = (const float*)d_in[7];
  const float* Wp    = (const float*)d_in[8];
  const float* bp    = (const float*)d_in[9];
  const float* ln_g  = (const float*)d_in[10];
  const float* ln_b  = (const float*)d_in[11];
  const float* bez   = (const float*)d_in[12];
  float* out = (float*)d_out;

  char* ws = (char*)d_ws;
  bf16_t* qb  = (bf16_t*)(ws);                          //  8 MB [B,H,T,D]
  bf16_t* kb_ = (bf16_t*)(ws + (size_t)8  * 1048576);   //  8 MB
  bf16_t* vb  = (bf16_t*)(ws + (size_t)16 * 1048576);   //  8 MB
  bf16_t* WT  = (bf16_t*)(ws + (size_t)24 * 1048576);   //  6 MB (WqT|WkT|WvT)
  bf16_t* pa  = (bf16_t*)(ws + (size_t)30 * 1048576);   //  8 MB proj A input (bf16)
  bf16_t* WpT = (bf16_t*)(ws + (size_t)38 * 1048576);   //  2.5 MB
  bf16_t* hb  = (bf16_t*)(ws + (size_t)41 * 1048576);   // 10 MB

  prep_kernel<<<PREP_GRID, 256, 0, stream>>>(Wp, WpT, x, pa, Wq, Wk, Wv, WT, gamma);
  gemm_qkv<<<dim3(24, 32), 256, 0, stream>>>(x, WT, bq, bk, bv, qb, kb_, vb, gamma);
  attn_kernel<<<dim3(32, 32), 256, 0, stream>>>(qb, kb_, vb, x, pa, gamma);
  gemm_proj<<<512, 256, 0, stream>>>(pa, WpT, bp, hb);
  ln_bezier<<<1024, 256, 0, stream>>>(hb, ln_g, ln_b, bez, out);
}